// Round 1
// baseline (6867.184 us; speedup 1.0000x reference)
//
#include <hip/hip_runtime.h>

#define DIM 128

// Generic scatter SpMM: for each edge e, dst[didx[e], :] += vals[e] * src[sidx[e], :]
// 32 threads per edge, 4 floats (float4) per thread.
__global__ void k_scatter(const int* __restrict__ didx, const int* __restrict__ sidx,
                          const float* __restrict__ vals, const float* __restrict__ src,
                          float* __restrict__ dst, long long nnz)
{
    long long t = (long long)blockIdx.x * blockDim.x + threadIdx.x;
    long long total = nnz * 32;
    if (t >= total) return;
    long long e = t >> 5;
    int d = (int)(t & 31) * 4;
    int si = sidx[e];
    int di = didx[e];
    float v = vals[e];
    const float4 s = *reinterpret_cast<const float4*>(src + (long long)si * DIM + d);
    float* p = dst + (long long)di * DIM + d;
    atomicAdd(p + 0, v * s.x);
    atomicAdd(p + 1, v * s.y);
    atomicAdd(p + 2, v * s.z);
    atomicAdd(p + 3, v * s.w);
}

// Per-user: cat = [node_msg, node_msg*user_emb]; msg = cat @ W^T + b.
// One block (128 threads) per user. node_msg is read from `msg` buffer and
// overwritten in place (each block owns its row; LDS copy + barrier first).
__global__ void k_msg(const float* __restrict__ user_emb, const float* __restrict__ W,
                      const float* __restrict__ b, float* __restrict__ msg)
{
    __shared__ float cat[2 * DIM];
    int u = blockIdx.x;
    int t = threadIdx.x;  // 0..127
    long long base = (long long)u * DIM;
    float nm = msg[base + t];
    float ue = user_emb[base + t];
    cat[t] = nm;
    cat[DIM + t] = nm * ue;
    __syncthreads();
    float acc = b[t];
    const float4* Wr = reinterpret_cast<const float4*>(W + (long long)t * 2 * DIM);
    const float4* c4 = reinterpret_cast<const float4*>(cat);
    #pragma unroll
    for (int k = 0; k < 2 * DIM / 4; ++k) {
        float4 w = Wr[k];
        float4 c = c4[k];
        acc += w.x * c.x + w.y * c.y + w.z * c.z + w.w * c.w;
    }
    msg[base + t] = acc;
}

extern "C" void kernel_launch(void* const* d_in, const int* in_sizes, int n_in,
                              void* d_out, int out_size, void* d_ws, size_t ws_size,
                              hipStream_t stream) {
    const float* user_emb = (const float*)d_in[0];
    const float* item_emb = (const float*)d_in[1];
    const int*   rows     = (const int*)d_in[2];
    const int*   cols     = (const int*)d_in[3];
    const float* vals     = (const float*)d_in[4];
    const float* W        = (const float*)d_in[5];
    const float* b        = (const float*)d_in[6];

    int n_users = in_sizes[0] / DIM;
    int n_items = in_sizes[1] / DIM;
    long long nnz = in_sizes[2];

    float* norm_emb = (float*)d_out;                                  // [n_items, DIM]
    float* msg      = (float*)d_out + (long long)n_items * DIM;       // [n_users, DIM]

    // Zero both output regions (msg region doubles as node_msg accumulator).
    hipMemsetAsync(d_out, 0, (size_t)out_size * sizeof(float), stream);

    long long tot = nnz * 32;
    int blk = 256;
    long long nblk = (tot + blk - 1) / blk;

    // node_msg = H @ item_emb   (into msg region)
    k_scatter<<<(int)nblk, blk, 0, stream>>>(rows, cols, vals, item_emb, msg, nnz);
    // msg = Linear(cat[node_msg, node_msg*user_emb])   (in place)
    k_msg<<<n_users, DIM, 0, stream>>>(user_emb, W, b, msg);
    // norm_emb = H^T @ msg
    k_scatter<<<(int)nblk, blk, 0, stream>>>(cols, rows, vals, msg, norm_emb, nnz);
}

// Round 2
// 860.418 us; speedup vs baseline: 7.9812x; 7.9812x over previous
//
#include <hip/hip_runtime.h>

#define DIM 128

// ======================= CSR build =======================

__global__ void k_count(const int* __restrict__ rows, const int* __restrict__ cols,
                        int* __restrict__ cnt_u, int* __restrict__ cnt_i, int nnz)
{
    int e = blockIdx.x * blockDim.x + threadIdx.x;
    int stride = gridDim.x * blockDim.x;
    for (; e < nnz; e += stride) {
        atomicAdd(&cnt_u[rows[e]], 1);
        atomicAdd(&cnt_i[cols[e]], 1);
    }
}

// phase 1: per-block exclusive scan of counts -> ptr, block sums -> partial
__global__ void k_scan1(const int* __restrict__ cnt, int* __restrict__ ptr,
                        int* __restrict__ partial, int n)
{
    __shared__ int s[256];
    int i = blockIdx.x * 256 + threadIdx.x;
    int v = (i < n) ? cnt[i] : 0;
    s[threadIdx.x] = v;
    __syncthreads();
    for (int off = 1; off < 256; off <<= 1) {
        int x = (threadIdx.x >= off) ? s[threadIdx.x - off] : 0;
        __syncthreads();
        s[threadIdx.x] += x;
        __syncthreads();
    }
    if (i < n) ptr[i] = s[threadIdx.x] - v;          // exclusive
    if (threadIdx.x == 255) partial[blockIdx.x] = s[255];
}

// phase 2: single-block exclusive scan of partials in place (n <= 512)
__global__ void k_scan2(int* __restrict__ partial, int n)
{
    __shared__ int s[512];
    int v = (threadIdx.x < (unsigned)n) ? partial[threadIdx.x] : 0;
    s[threadIdx.x] = v;
    __syncthreads();
    for (int off = 1; off < 512; off <<= 1) {
        int x = (threadIdx.x >= off) ? s[threadIdx.x - off] : 0;
        __syncthreads();
        s[threadIdx.x] += x;
        __syncthreads();
    }
    if (threadIdx.x < (unsigned)n) partial[threadIdx.x] = s[threadIdx.x] - v;
}

// phase 3: add block offsets, copy to running-offset array, write ptr[n]
__global__ void k_scan3(int* __restrict__ ptr, const int* __restrict__ partial,
                        int* __restrict__ woff, int n, int total)
{
    int i = blockIdx.x * 256 + threadIdx.x;
    if (i < n) {
        int p = ptr[i] + partial[blockIdx.x];
        ptr[i] = p;
        woff[i] = p;
        if (i == n - 1) ptr[n] = total;
    }
}

__global__ void k_edge_scatter(const int* __restrict__ rows, const int* __restrict__ cols,
                               const float* __restrict__ vals,
                               int* __restrict__ woff_u, int* __restrict__ woff_i,
                               int* __restrict__ cs_u_col, float* __restrict__ cs_u_val,
                               int* __restrict__ cs_i_row, float* __restrict__ cs_i_val,
                               int nnz)
{
    int e = blockIdx.x * blockDim.x + threadIdx.x;
    int stride = gridDim.x * blockDim.x;
    for (; e < nnz; e += stride) {
        int r = rows[e], c = cols[e];
        float v = vals[e];
        int pu = atomicAdd(&woff_u[r], 1);
        cs_u_col[pu] = c; cs_u_val[pu] = v;
        int pi = atomicAdd(&woff_i[c], 1);
        cs_i_row[pi] = r; cs_i_val[pi] = v;
    }
}

// ======================= gather SpMM =======================
// dst[r,:] = sum_j val[j] * src[idx[j],:]   for j in [ptr[r], ptr[r+1])
// one wave (64 lanes) per row; float2 per lane.
__global__ void k_spmm(const int* __restrict__ ptr, const int* __restrict__ idx,
                       const float* __restrict__ val, const float* __restrict__ src,
                       float* __restrict__ dst, int nrows)
{
    int r = blockIdx.x * 4 + (threadIdx.x >> 6);
    if (r >= nrows) return;
    int l = threadIdx.x & 63;
    int beg = ptr[r], end = ptr[r + 1];
    float2 a0 = {0.f, 0.f}, a1 = {0.f, 0.f};
    int j = beg;
    for (; j + 1 < end; j += 2) {
        int c0 = idx[j], c1 = idx[j + 1];
        float v0 = val[j], v1 = val[j + 1];
        float2 s0 = *reinterpret_cast<const float2*>(src + (long long)c0 * DIM + 2 * l);
        float2 s1 = *reinterpret_cast<const float2*>(src + (long long)c1 * DIM + 2 * l);
        a0.x += v0 * s0.x; a0.y += v0 * s0.y;
        a1.x += v1 * s1.x; a1.y += v1 * s1.y;
    }
    if (j < end) {
        int c0 = idx[j];
        float v0 = val[j];
        float2 s0 = *reinterpret_cast<const float2*>(src + (long long)c0 * DIM + 2 * l);
        a0.x += v0 * s0.x; a0.y += v0 * s0.y;
    }
    a0.x += a1.x; a0.y += a1.y;
    *reinterpret_cast<float2*>(dst + (long long)r * DIM + 2 * l) = a0;
}

// ======================= per-user linear =======================
// msg[u,:] = [node_msg[u], node_msg[u]*user_emb[u]] @ W^T + b
// 1 wave per 16 users; thread t computes out dims t and t+64.
__global__ void k_msg2(const float* __restrict__ node_msg, const float* __restrict__ user_emb,
                       const float* __restrict__ W, const float* __restrict__ b,
                       float* __restrict__ msg, int n_users)
{
    __shared__ float cat[16 * 256];
    int t = threadIdx.x;           // 0..63
    int u0 = blockIdx.x * 16;
    for (int idx = t; idx < 16 * DIM; idx += 64) {
        int u = idx >> 7, d = idx & 127;
        if (u0 + u < n_users) {
            long long g = (long long)(u0 + u) * DIM + d;
            float nm = node_msg[g];
            float ue = user_emb[g];
            cat[u * 256 + d] = nm;
            cat[u * 256 + DIM + d] = nm * ue;
        }
    }
    __syncthreads();
    float acc0[16], acc1[16];
    #pragma unroll
    for (int u = 0; u < 16; ++u) { acc0[u] = 0.f; acc1[u] = 0.f; }
    float b0 = b[t], b1 = b[t + 64];
    const float4* W0 = reinterpret_cast<const float4*>(W + (long long)t * 256);
    const float4* W1 = reinterpret_cast<const float4*>(W + (long long)(t + 64) * 256);
    for (int k4 = 0; k4 < 64; ++k4) {
        float4 w0 = W0[k4];
        float4 w1 = W1[k4];
        #pragma unroll
        for (int u = 0; u < 16; ++u) {
            float4 c = *reinterpret_cast<const float4*>(&cat[u * 256 + k4 * 4]);
            acc0[u] += w0.x * c.x + w0.y * c.y + w0.z * c.z + w0.w * c.w;
            acc1[u] += w1.x * c.x + w1.y * c.y + w1.z * c.z + w1.w * c.w;
        }
    }
    for (int u = 0; u < 16; ++u) {
        if (u0 + u >= n_users) break;
        long long g = (long long)(u0 + u) * DIM;
        msg[g + t] = acc0[u] + b0;
        msg[g + t + 64] = acc1[u] + b1;
    }
}

// ======================= fallback (atomic path, R1) =======================

__global__ void k_scatter(const int* __restrict__ didx, const int* __restrict__ sidx,
                          const float* __restrict__ vals, const float* __restrict__ src,
                          float* __restrict__ dst, long long nnz)
{
    long long t = (long long)blockIdx.x * blockDim.x + threadIdx.x;
    long long total = nnz * 32;
    if (t >= total) return;
    long long e = t >> 5;
    int d = (int)(t & 31) * 4;
    int si = sidx[e];
    int di = didx[e];
    float v = vals[e];
    const float4 s = *reinterpret_cast<const float4*>(src + (long long)si * DIM + d);
    float* p = dst + (long long)di * DIM + d;
    atomicAdd(p + 0, v * s.x);
    atomicAdd(p + 1, v * s.y);
    atomicAdd(p + 2, v * s.z);
    atomicAdd(p + 3, v * s.w);
}

__global__ void k_msg_simple(const float* __restrict__ user_emb, const float* __restrict__ W,
                             const float* __restrict__ b, float* __restrict__ msg)
{
    __shared__ float cat[2 * DIM];
    int u = blockIdx.x;
    int t = threadIdx.x;
    long long base = (long long)u * DIM;
    float nm = msg[base + t];
    float ue = user_emb[base + t];
    cat[t] = nm;
    cat[DIM + t] = nm * ue;
    __syncthreads();
    float acc = b[t];
    const float4* Wr = reinterpret_cast<const float4*>(W + (long long)t * 2 * DIM);
    const float4* c4 = reinterpret_cast<const float4*>(cat);
    #pragma unroll
    for (int k = 0; k < 2 * DIM / 4; ++k) {
        float4 w = Wr[k];
        float4 c = c4[k];
        acc += w.x * c.x + w.y * c.y + w.z * c.z + w.w * c.w;
    }
    msg[base + t] = acc;
}

// ======================= launch =======================

extern "C" void kernel_launch(void* const* d_in, const int* in_sizes, int n_in,
                              void* d_out, int out_size, void* d_ws, size_t ws_size,
                              hipStream_t stream) {
    const float* user_emb = (const float*)d_in[0];
    const float* item_emb = (const float*)d_in[1];
    const int*   rows     = (const int*)d_in[2];
    const int*   cols     = (const int*)d_in[3];
    const float* vals     = (const float*)d_in[4];
    const float* W        = (const float*)d_in[5];
    const float* b        = (const float*)d_in[6];

    int nu = in_sizes[0] / DIM;
    int ni = in_sizes[1] / DIM;
    int nnz = in_sizes[2];

    float* norm_emb = (float*)d_out;                              // [ni, DIM]
    float* msg      = (float*)d_out + (long long)ni * DIM;        // [nu, DIM] (doubles as node_msg)

    // ---- ws layout ----
    auto align256 = [](size_t x) { return (x + 255) & ~(size_t)255; };
    size_t off = 0;
    size_t o_cs_u_col = off; off = align256(off + (size_t)nnz * 4);
    size_t o_cs_u_val = off; off = align256(off + (size_t)nnz * 4);
    size_t o_cs_i_row = off; off = align256(off + (size_t)nnz * 4);
    size_t o_cs_i_val = off; off = align256(off + (size_t)nnz * 4);
    size_t o_ptr_u    = off; off = align256(off + (size_t)(nu + 1) * 4);
    size_t o_ptr_i    = off; off = align256(off + (size_t)(ni + 1) * 4);
    size_t o_woff_u   = off; off = align256(off + (size_t)nu * 4);
    size_t o_woff_i   = off; off = align256(off + (size_t)ni * 4);
    size_t o_part_u   = off; off = align256(off + 512 * 4);
    size_t o_part_i   = off; off = align256(off + 512 * 4);
    size_t need = off;

    int npb_u = (nu + 255) / 256;
    int npb_i = (ni + 255) / 256;

    if (ws_size >= need && npb_u <= 512 && npb_i <= 512) {
        char* ws = (char*)d_ws;
        int*   cs_u_col = (int*)(ws + o_cs_u_col);
        float* cs_u_val = (float*)(ws + o_cs_u_val);
        int*   cs_i_row = (int*)(ws + o_cs_i_row);
        float* cs_i_val = (float*)(ws + o_cs_i_val);
        int*   ptr_u    = (int*)(ws + o_ptr_u);
        int*   ptr_i    = (int*)(ws + o_ptr_i);
        int*   woff_u   = (int*)(ws + o_woff_u);
        int*   woff_i   = (int*)(ws + o_woff_i);
        int*   part_u   = (int*)(ws + o_part_u);
        int*   part_i   = (int*)(ws + o_part_i);

        hipMemsetAsync(woff_u, 0, (size_t)nu * 4, stream);
        hipMemsetAsync(woff_i, 0, (size_t)ni * 4, stream);

        int gs = 2048;
        k_count<<<gs, 256, 0, stream>>>(rows, cols, woff_u, woff_i, nnz);

        k_scan1<<<npb_u, 256, 0, stream>>>(woff_u, ptr_u, part_u, nu);
        k_scan1<<<npb_i, 256, 0, stream>>>(woff_i, ptr_i, part_i, ni);
        k_scan2<<<1, 512, 0, stream>>>(part_u, npb_u);
        k_scan2<<<1, 512, 0, stream>>>(part_i, npb_i);
        k_scan3<<<npb_u, 256, 0, stream>>>(ptr_u, part_u, woff_u, nu, nnz);
        k_scan3<<<npb_i, 256, 0, stream>>>(ptr_i, part_i, woff_i, ni, nnz);

        k_edge_scatter<<<gs, 256, 0, stream>>>(rows, cols, vals, woff_u, woff_i,
                                               cs_u_col, cs_u_val, cs_i_row, cs_i_val, nnz);

        // node_msg = H @ item_emb  -> msg region
        k_spmm<<<(nu + 3) / 4, 256, 0, stream>>>(ptr_u, cs_u_col, cs_u_val, item_emb, msg, nu);
        // msg = Linear(cat)
        k_msg2<<<(nu + 15) / 16, 64, 0, stream>>>(msg, user_emb, W, b, msg, nu);
        // norm_emb = H^T @ msg
        k_spmm<<<(ni + 3) / 4, 256, 0, stream>>>(ptr_i, cs_i_row, cs_i_val, msg, norm_emb, ni);
    } else {
        // fallback: atomic path
        hipMemsetAsync(d_out, 0, (size_t)out_size * sizeof(float), stream);
        long long tot = (long long)nnz * 32;
        int blk = 256;
        long long nblk = (tot + blk - 1) / blk;
        k_scatter<<<(int)nblk, blk, 0, stream>>>(rows, cols, vals, item_emb, msg, nnz);
        k_msg_simple<<<nu, DIM, 0, stream>>>(user_emb, W, b, msg);
        k_scatter<<<(int)nblk, blk, 0, stream>>>(cols, rows, vals, msg, norm_emb, nnz);
    }
}